// Round 6
// baseline (157.423 us; speedup 1.0000x reference)
//
#include <hip/hip_runtime.h>

// rmsdLoss via associative affine scan — 4 waves/row (2 per chain), CHUNK=8.
// Step j (j=0..1020) is the rigid map  p -> p + F*(l*what_j) ; F -> F*R_j,
//   what_j = (-ct, st*cc, st*sc) (unit), l = bl[2+j],
//   R_j columns: [ what | (-st, -ct*cc, -ct*sc) | (0, -sc, cc) ].
// Chunk elements (M,t) combine as (Ma*Mb, ta + Ma*tb).
// Block = 256 threads = 4 waves: wv 0,1 = pred (clipped), wv 2,3 = targ.
// Chunk index m = 64*(wv&1)+ln owns steps [8m, 8m+8).
// Rows staged coalesced into stride-33-padded LDS images (<=2-way bank alias).
// In-wave 6-level shuffle scan + one inter-wave combine (192 B LDS) gives the
// exclusive prefix; fold (F0,a2) -> G; replay 8 steps on G (position = G.t).
// Pred positions cross to targ waves by REUSING pred's dead staging buffer.

#define LROW  4087
#define NSTEP 1021
#define NROW  2048
#define CHUNK 8
#define SSZ   (128 * 33)     // 4224 floats per padded row image
#define EPSF  1e-6f
#define INVMEAN (1.0f / (2048.0f * 1024.0f * 3.0f))

__device__ __forceinline__ float frcp(float x){ return __builtin_amdgcn_rcpf(x); }
__device__ __forceinline__ int   padi(int i){ return (i >> 5) * 33 + (i & 31); }

struct Xf { float f[12]; };  // f[0..8] = M row-major, f[9..11] = t

__device__ __forceinline__ Xf xident(){
  Xf X;
  X.f[0]=1.f; X.f[1]=0.f; X.f[2]=0.f;
  X.f[3]=0.f; X.f[4]=1.f; X.f[5]=0.f;
  X.f[6]=0.f; X.f[7]=0.f; X.f[8]=1.f;
  X.f[9]=0.f; X.f[10]=0.f; X.f[11]=0.f;
  return X;
}

// A applied first, then B:  (Ma*Mb, ta + Ma*tb)
__device__ __forceinline__ Xf xcombine(const Xf& A, const Xf& B){
  Xf C;
  #pragma unroll
  for (int r = 0; r < 3; ++r){
    const float a0 = A.f[3*r], a1 = A.f[3*r+1], a2 = A.f[3*r+2];
    C.f[3*r]   = a0*B.f[0] + a1*B.f[3] + a2*B.f[6];
    C.f[3*r+1] = a0*B.f[1] + a1*B.f[4] + a2*B.f[7];
    C.f[3*r+2] = a0*B.f[2] + a1*B.f[5] + a2*B.f[8];
    C.f[9+r]   = A.f[9+r] + a0*B.f[9] + a1*B.f[10] + a2*B.f[11];
  }
  return C;
}

struct Coef { float l, ct, st, cc, sc; };

// running (M,t) <- combine(running, step): t += M*(l*what) ; M <- M*R
__device__ __forceinline__ void xstep(Xf& X, const Coef& k){
  const float w0 = -k.ct, w1 = k.st*k.cc, w2 = k.st*k.sc;   // unit what
  const float ux = X.f[0]*w0 + X.f[1]*w1 + X.f[2]*w2;
  const float uy = X.f[3]*w0 + X.f[4]*w1 + X.f[5]*w2;
  const float uz = X.f[6]*w0 + X.f[7]*w1 + X.f[8]*w2;
  X.f[9]  = fmaf(k.l, ux, X.f[9]);
  X.f[10] = fmaf(k.l, uy, X.f[10]);
  X.f[11] = fmaf(k.l, uz, X.f[11]);
  const float a = -k.st, b = -k.ct*k.cc, d = -k.ct*k.sc;
  const float n1x = a*X.f[0] + b*X.f[1] + d*X.f[2];
  const float n1y = a*X.f[3] + b*X.f[4] + d*X.f[5];
  const float n1z = a*X.f[6] + b*X.f[7] + d*X.f[8];
  const float n2x = -k.sc*X.f[1] + k.cc*X.f[2];
  const float n2y = -k.sc*X.f[4] + k.cc*X.f[5];
  const float n2z = -k.sc*X.f[7] + k.cc*X.f[8];
  X.f[0] = ux; X.f[1] = n1x; X.f[2] = n2x;
  X.f[3] = uy; X.f[4] = n1y; X.f[5] = n2y;
  X.f[6] = uz; X.f[7] = n1z; X.f[8] = n2z;
}

// X = first step directly (identity composed with step)
__device__ __forceinline__ void xinit(Xf& X, const Coef& k){
  X.f[0] = -k.ct;      X.f[1] = -k.st;      X.f[2] = 0.f;
  X.f[3] = k.st*k.cc;  X.f[4] = -k.ct*k.cc; X.f[5] = -k.sc;
  X.f[6] = k.st*k.sc;  X.f[7] = -k.ct*k.sc; X.f[8] = k.cc;
  X.f[9] = k.l*X.f[0]; X.f[10] = k.l*X.f[3]; X.f[11] = k.l*X.f[6];
}

__device__ __forceinline__ Coef mkcoef(float s0, float s1, float rd, float rb1, float rb2){
  const float d  = fmaf(rd,  1.75f, 3.25f);
  const float b1 = fmaf(rb1, 1.05f, 1.95f);
  const float b2 = fmaf(rb2, 1.05f, 1.95f);
  float ct = (b1*b1 + b2*b2 - d*d) * frcp(2.0f*b1*b2);
  ct = fminf(fmaxf(ct, -1.0f + EPSF), 1.0f - EPSF);
  const float st = sqrtf(fmaxf(1.0f - ct*ct, 0.0f));
  const float r2 = s0*s0 + s1*s1;
  const bool ok = r2 > 1e-36f;
  const float ir = ok ? frcp(sqrtf(r2)) : 0.0f;
  Coef K;
  K.sc = s0 * ir;
  K.cc = ok ? s1 * ir : 1.0f;
  K.ct = ct; K.st = st; K.l = b2;
  return K;
}

__global__ void __launch_bounds__(256, 4)
rmsd_kernel(const float* __restrict__ pred, const float* __restrict__ targ,
            float* __restrict__ out){
  __shared__ float sbuf[2][SSZ];   // 33.8 KB padded row images
  __shared__ float xch[4][12];     // per-wave scan totals
  __shared__ float ini[3];         // pred a1x, a2x, a2y

  const int row = blockIdx.x;
  const int tid = threadIdx.x;
  const int ln  = tid & 63;
  const int wv  = tid >> 6;            // 0..3
  const int ch  = wv >> 1;             // 0 = pred, 1 = targ
  const int m   = ((wv & 1) << 6) | ln; // chunk 0..127
  const int j0  = m * CHUNK;

  const float* __restrict__ vp = pred + (size_t)row * LROW;
  const float* __restrict__ vt = targ + (size_t)row * LROW;

  // ---- stage both rows coalesced into padded LDS (clip pred at staging) ----
  #pragma unroll 4
  for (int u = tid; u < 2 * LROW; u += 256){
    if (u < LROW){
      sbuf[0][padi(u)] = fminf(fmaxf(vp[u], -1.0f), 1.0f);
    } else {
      const int i = u - LROW;
      sbuf[1][padi(i)] = vt[i];
    }
  }
  __syncthreads();

  const float* __restrict__ S = sbuf[ch];
  auto rdS = [&](int idx) -> float { return S[padi(idx)]; };
  auto coefAt = [&](int j) -> Coef {
    return mkcoef(rdS(2*j), rdS(2*j+1), rdS(2043+j), rdS(3065+j), rdS(3066+j));
  };

  // ---- phase 1: per-lane chunk compose (8 steps) ----
  Xf X;
  xinit(X, coefAt(j0));              // j0 <= 1016 < NSTEP always
  #pragma unroll
  for (int k = 1; k < CHUNK; ++k){
    const int j = j0 + k;
    if (j < NSTEP) xstep(X, coefAt(j));
  }

  // ---- in-wave inclusive scan (Hillis-Steele, non-commutative) ----
  #pragma unroll
  for (int off = 1; off < 64; off <<= 1){
    Xf o;
    #pragma unroll
    for (int i = 0; i < 12; ++i) o.f[i] = __shfl_up(X.f[i], off);
    if (ln >= off) X = xcombine(o, X);
  }
  if (ln == 63){
    #pragma unroll
    for (int i = 0; i < 12; ++i) xch[wv][i] = X.f[i];
  }
  // exclusive prefix within wave
  Xf E;
  #pragma unroll
  for (int i = 0; i < 12; ++i) E.f[i] = __shfl_up(X.f[i], 1);
  if (ln == 0) E = xident();
  __syncthreads();

  // ---- inter-wave: odd waves prepend the even wave's chunk total ----
  if (wv & 1){
    Xf T;
    #pragma unroll
    for (int i = 0; i < 12; ++i) T.f[i] = xch[wv - 1][i];
    E = xcombine(T, E);
  }

  // ---- fold (F0, a2): G = F0*E.M ; G.t = a2 + F0*E.t ----
  const float bl0 = fmaf(rdS(3064), 1.05f, 1.95f);
  const float d0  = fmaf(rdS(2042), 1.75f, 3.25f);
  const float b1  = fmaf(rdS(3065), 1.05f, 1.95f);
  float ct0 = (bl0*bl0 + b1*b1 - d0*d0) * frcp(2.0f*bl0*b1);
  ct0 = fminf(fmaxf(ct0, -1.0f + EPSF), 1.0f - EPSF);
  const float st0 = sqrtf(fmaxf(1.0f - ct0*ct0, 0.0f));
  const float a1x = bl0;
  const float a2x = bl0 - b1*ct0;
  const float a2y = b1*st0;

  Xf G;   // F0 rows: (-ct0,-st0,0),(st0,-ct0,0),(0,0,1)
  G.f[0] = -ct0*E.f[0] - st0*E.f[3];
  G.f[1] = -ct0*E.f[1] - st0*E.f[4];
  G.f[2] = -ct0*E.f[2] - st0*E.f[5];
  G.f[3] =  st0*E.f[0] - ct0*E.f[3];
  G.f[4] =  st0*E.f[1] - ct0*E.f[4];
  G.f[5] =  st0*E.f[2] - ct0*E.f[5];
  G.f[6] = E.f[6]; G.f[7] = E.f[7]; G.f[8] = E.f[8];
  G.f[9]  = a2x - ct0*E.f[9] - st0*E.f[10];
  G.f[10] = a2y + st0*E.f[9] - ct0*E.f[10];
  G.f[11] = E.f[11];

  // ---- replay: position after step j is G.t after composing step j ----
  float p[CHUNK][3];
  #pragma unroll
  for (int k = 0; k < CHUNK; ++k){
    const int j = j0 + k;
    if (j < NSTEP){
      xstep(G, coefAt(j));
      p[k][0] = G.f[9]; p[k][1] = G.f[10]; p[k][2] = G.f[11];
    }
  }
  __syncthreads();   // pred staging now dead everywhere

  // ---- pred waves publish positions into pred's dead staging buffer ----
  float* __restrict__ pos = &sbuf[0][0];   // offset(j) = 3j + (j>>3), max 3196 < SSZ
  if (ch == 0){
    #pragma unroll
    for (int k = 0; k < CHUNK; ++k){
      const int j = j0 + k;
      if (j < NSTEP){
        const int o = 3*j + (j >> 3);
        pos[o] = p[k][0]; pos[o+1] = p[k][1]; pos[o+2] = p[k][2];
      }
    }
    if (wv == 0 && ln == 0){ ini[0] = a1x; ini[1] = a2x; ini[2] = a2y; }
  }
  __syncthreads();

  // ---- targ waves diff + reduce ----
  if (ch == 1){
    float acc = 0.0f;
    if (wv == 2 && ln == 0){
      const float dx = ini[0] - a1x;   // a1 differs only in x; a0 diff = 0
      const float dy = ini[1] - a2x;   // a2 differs in x,y (z = 0)
      const float dz = ini[2] - a2y;
      acc = dx*dx + dy*dy + dz*dz;
    }
    #pragma unroll
    for (int k = 0; k < CHUNK; ++k){
      const int j = j0 + k;
      if (j < NSTEP){
        const int o = 3*j + (j >> 3);
        const float dx = pos[o]   - p[k][0];
        const float dy = pos[o+1] - p[k][1];
        const float dz = pos[o+2] - p[k][2];
        acc = fmaf(dx, dx, acc);
        acc = fmaf(dy, dy, acc);
        acc = fmaf(dz, dz, acc);
      }
    }
    #pragma unroll
    for (int off = 32; off > 0; off >>= 1) acc += __shfl_down(acc, off);
    if (ln == 0) atomicAdd(out, acc * INVMEAN);
  }
}

extern "C" void kernel_launch(void* const* d_in, const int* in_sizes, int n_in,
                              void* d_out, int out_size, void* d_ws, size_t ws_size,
                              hipStream_t stream) {
  const float* pred = (const float*)d_in[0];
  const float* targ = (const float*)d_in[1];
  float* out = (float*)d_out;

  hipMemsetAsync(d_out, 0, sizeof(float), stream);
  rmsd_kernel<<<NROW, 256, 0, stream>>>(pred, targ, out);
}

// Round 8
// 131.350 us; speedup vs baseline: 1.1985x; 1.1985x over previous
//
#include <hip/hip_runtime.h>

// rmsdLoss via associative affine scan — one wave per chain, CHUNK=16,
// LDS holds precomputed step vectors P_j = l*what_j (3 floats/step) in a
// k-major transposed layout (phase-1 reads stride-1, conflict-free).
// Step algebra on P alone:  q = rsqrt(P.P), what = q*P = (hx,hy,hz),
//   st^2 = hy^2 + hz^2  (NO 1-hx^2 cancellation!), ist = rsqrt(hy^2+hz^2);
//   u = M*P; t += u; c0' = q*u; c1' = ist*(hx*c0' - c0); c2' = ist*(hy*c2 - hz*c1).
// Frame columns stay unit to ~1e-7 even when the ct clamp binds (st ~ 1.4e-3),
// unlike the 1-hx^2 form which loses ~3% per clamped step (R7 bug).
// Block = 128 thr = 2 waves: wv0 = pred (clipped), wv1 = targ; lane ln owns
// steps [16ln,16ln+16). 6-level shuffle scan -> exclusive prefix E; fold
// (F0,a2) -> G; positions p_k = G.t + G.M*tl[k] (snapshot, no replay).
// Pred positions cross via pitch-49 pos buffer aliasing pred's dead P plane.

#define LROW  4087
#define NSTEP 1021
#define NROW  2048
#define CHUNK 16
#define PP    66                 // k-slab pitch
#define PSZ   (CHUNK * PP)       // 1056 floats per component plane
#define EPSF  1e-6f
#define INVMEAN (1.0f / (2048.0f * 1024.0f * 3.0f))

__device__ __forceinline__ float frcp(float x){ return __builtin_amdgcn_rcpf(x); }
__device__ __forceinline__ float frsq(float x){ return __builtin_amdgcn_rsqf(x); }

struct Xf { float f[12]; };  // COLUMN-major: f[0..2]=c0, f[3..5]=c1, f[6..8]=c2, f[9..11]=t

__device__ __forceinline__ Xf xident(){
  Xf X;
  X.f[0]=1.f; X.f[1]=0.f; X.f[2]=0.f;
  X.f[3]=0.f; X.f[4]=1.f; X.f[5]=0.f;
  X.f[6]=0.f; X.f[7]=0.f; X.f[8]=1.f;
  X.f[9]=0.f; X.f[10]=0.f; X.f[11]=0.f;
  return X;
}

// A applied first, then B: C.M = A.M*B.M (columns), C.t = A.t + A.M*B.t
__device__ __forceinline__ Xf xcombine(const Xf& A, const Xf& B){
  Xf C;
  #pragma unroll
  for (int c3 = 0; c3 < 12; c3 += 3){
    const float bx = B.f[c3], by = B.f[c3+1], bz = B.f[c3+2];
    C.f[c3]   = A.f[0]*bx + A.f[3]*by + A.f[6]*bz;
    C.f[c3+1] = A.f[1]*bx + A.f[4]*by + A.f[7]*bz;
    C.f[c3+2] = A.f[2]*bx + A.f[5]*by + A.f[8]*bz;
  }
  C.f[9] += A.f[9]; C.f[10] += A.f[10]; C.f[11] += A.f[11];
  return C;
}

__device__ __forceinline__ void xstepP(Xf& X, float Px, float Py, float Pz){
  const float l2 = Px*Px + Py*Py + Pz*Pz;
  const float q  = frsq(l2);
  const float hx = q*Px, hy = q*Py, hz = q*Pz;
  const float ist = frsq(fmaxf(hy*hy + hz*hz, 1e-12f));   // 1/st, cancellation-free
  const float ux = X.f[0]*Px + X.f[3]*Py + X.f[6]*Pz;
  const float uy = X.f[1]*Px + X.f[4]*Py + X.f[7]*Pz;
  const float uz = X.f[2]*Px + X.f[5]*Py + X.f[8]*Pz;
  X.f[9] += ux; X.f[10] += uy; X.f[11] += uz;
  const float n0x = q*ux, n0y = q*uy, n0z = q*uz;
  const float n1x = ist*(hx*n0x - X.f[0]);
  const float n1y = ist*(hx*n0y - X.f[1]);
  const float n1z = ist*(hx*n0z - X.f[2]);
  const float n2x = ist*(hy*X.f[6] - hz*X.f[3]);
  const float n2y = ist*(hy*X.f[7] - hz*X.f[4]);
  const float n2z = ist*(hy*X.f[8] - hz*X.f[5]);
  X.f[0]=n0x; X.f[1]=n0y; X.f[2]=n0z;
  X.f[3]=n1x; X.f[4]=n1y; X.f[5]=n1z;
  X.f[6]=n2x; X.f[7]=n2y; X.f[8]=n2z;
}

__device__ __forceinline__ void xinitP(Xf& X, float Px, float Py, float Pz){
  const float l2 = Px*Px + Py*Py + Pz*Pz;
  const float q  = frsq(l2);
  const float hx = q*Px, hy = q*Py, hz = q*Pz;
  const float s2 = fmaxf(hy*hy + hz*hz, 1e-12f);
  const float ist = frsq(s2);
  const float st  = s2 * ist;                 // sqrt(hy^2+hz^2), cancellation-free
  X.f[0]=hx;        X.f[1]=hy;          X.f[2]=hz;
  X.f[3]=-st;       X.f[4]=hx*hy*ist;   X.f[5]=hx*hz*ist;   // (-st, hx*cc, hx*sc)
  X.f[6]=0.f;       X.f[7]=-hz*ist;     X.f[8]=hy*ist;      // (0, -sc, cc)
  X.f[9]=Px;        X.f[10]=Py;         X.f[11]=Pz;
}

__global__ void __launch_bounds__(128, 3)
rmsd_kernel(const float* __restrict__ pred, const float* __restrict__ targ,
            float* __restrict__ out){
  __shared__ float P[2][3][PSZ];   // 25.3 KB
  __shared__ float ini[3];         // pred a1x, a2x, a2y

  const int row = blockIdx.x;
  const int tid = threadIdx.x;
  const int ln  = tid & 63;
  const int wv  = tid >> 6;      // 0 = pred, 1 = targ
  const int j0  = ln * CHUNK;

  const float* __restrict__ vp = pred + (size_t)row * LROW;
  const float* __restrict__ vt = targ + (size_t)row * LROW;

  // early broadcast loads for the fold (own chain)
  const float* vw = wv ? vt : vp;
  const float lw = wv ? 1e30f : 1.0f;
  const float rb0 = fminf(fmaxf(vw[3064], -lw), lw);
  const float rd0 = fminf(fmaxf(vw[2042], -lw), lw);
  const float rb1w= fminf(fmaxf(vw[3065], -lw), lw);

  // ---- staging: compute P_j = l*what_j into k-major padded LDS ----
  for (int u = tid; u < 2048; u += 128){
    const int c = u >> 10;
    const int j = u & 1023;
    if (j < NSTEP){
      const float* v = c ? vt : vp;
      const float cl = c ? 1e30f : 1.0f;     // reference clips pred only
      const float s0  = fminf(fmaxf(v[2*j],    -cl), cl);
      const float s1  = fminf(fmaxf(v[2*j+1],  -cl), cl);
      const float rd  = fminf(fmaxf(v[2043+j], -cl), cl);
      const float rb1 = fminf(fmaxf(v[3065+j], -cl), cl);
      const float rb2 = fminf(fmaxf(v[3066+j], -cl), cl);
      const float d  = fmaf(rd,  1.75f, 3.25f);
      const float b1 = fmaf(rb1, 1.05f, 1.95f);
      const float b2 = fmaf(rb2, 1.05f, 1.95f);
      float ct = (b1*b1 + b2*b2 - d*d) * frcp(2.0f*b1*b2);
      ct = fminf(fmaxf(ct, -1.0f + EPSF), 1.0f - EPSF);
      const float st = sqrtf(fmaxf(1.0f - ct*ct, 0.0f));
      const float r2 = s0*s0 + s1*s1;
      const bool ok = r2 > 1e-36f;
      const float ir = ok ? frcp(sqrtf(r2)) : 0.0f;
      const float scv = s0 * ir;
      const float ccv = ok ? s1 * ir : 1.0f;
      const int a = (j & 15) * PP + (j >> 4);
      P[c][0][a] = -b2 * ct;
      P[c][1][a] =  b2 * st * ccv;
      P[c][2][a] =  b2 * st * scv;
    }
  }
  __syncthreads();

  const float* Q0 = &P[wv][0][0];
  const float* Q1 = &P[wv][1][0];
  const float* Q2 = &P[wv][2][0];

  // ---- phase 1: per-lane chunk compose, snapshot local-prefix translations ----
  Xf X;
  float tl[CHUNK][3];
  xinitP(X, Q0[ln], Q1[ln], Q2[ln]);      // k=0; j0 < NSTEP always
  tl[0][0]=X.f[9]; tl[0][1]=X.f[10]; tl[0][2]=X.f[11];
  #pragma unroll
  for (int k = 1; k < CHUNK; ++k){
    if (j0 + k < NSTEP){
      const int a = k*PP + ln;
      xstepP(X, Q0[a], Q1[a], Q2[a]);
    }
    tl[k][0]=X.f[9]; tl[k][1]=X.f[10]; tl[k][2]=X.f[11];
  }

  // ---- in-wave inclusive scan (Hillis-Steele, non-commutative) ----
  #pragma unroll
  for (int off = 1; off < 64; off <<= 1){
    Xf o;
    #pragma unroll
    for (int i = 0; i < 12; ++i) o.f[i] = __shfl_up(X.f[i], off);
    if (ln >= off) X = xcombine(o, X);
  }
  Xf E;
  #pragma unroll
  for (int i = 0; i < 12; ++i) E.f[i] = __shfl_up(X.f[i], 1);
  if (ln == 0) E = xident();

  // ---- fold (F0, a2): G = F0*E.M ; G.t = a2 + F0*E.t ----
  const float bl0 = fmaf(rb0,  1.05f, 1.95f);
  const float d0  = fmaf(rd0,  1.75f, 3.25f);
  const float b1f = fmaf(rb1w, 1.05f, 1.95f);
  float ct0 = (bl0*bl0 + b1f*b1f - d0*d0) * frcp(2.0f*bl0*b1f);
  ct0 = fminf(fmaxf(ct0, -1.0f + EPSF), 1.0f - EPSF);
  const float st0 = sqrtf(fmaxf(1.0f - ct0*ct0, 0.0f));
  const float a1x = bl0;
  const float a2x = bl0 - b1f*ct0;
  const float a2y = b1f*st0;

  Xf G;   // F0 rows: (-ct0,-st0,0),(st0,-ct0,0),(0,0,1) applied to each column + t
  #pragma unroll
  for (int c3 = 0; c3 < 12; c3 += 3){
    const float ex = E.f[c3], ey = E.f[c3+1], ez = E.f[c3+2];
    G.f[c3]   = -ct0*ex - st0*ey;
    G.f[c3+1] =  st0*ex - ct0*ey;
    G.f[c3+2] =  ez;
  }
  G.f[9] += a2x; G.f[10] += a2y;

  // ---- positions p_k = G.t + G.M * tl[k]  (in place) ----
  #pragma unroll
  for (int k = 0; k < CHUNK; ++k){
    const float tx = tl[k][0], ty = tl[k][1], tz = tl[k][2];
    tl[k][0] = G.f[9]  + G.f[0]*tx + G.f[3]*ty + G.f[6]*tz;
    tl[k][1] = G.f[10] + G.f[1]*tx + G.f[4]*ty + G.f[7]*tz;
    tl[k][2] = G.f[11] + G.f[2]*tx + G.f[5]*ty + G.f[8]*tz;
  }

  // ---- pred publishes positions; pos aliases pred's dead P plane ----
  float* pos = &P[0][0][0];   // pitch 49: max offset 63*49+45+2 = 3134 < 3168
  if (wv == 0){
    #pragma unroll
    for (int k = 0; k < CHUNK; ++k){
      if (j0 + k < NSTEP){
        const int o = ln*49 + 3*k;
        pos[o] = tl[k][0]; pos[o+1] = tl[k][1]; pos[o+2] = tl[k][2];
      }
    }
    if (ln == 0){ ini[0] = a1x; ini[1] = a2x; ini[2] = a2y; }
  }
  __syncthreads();

  // ---- targ wave: diff + reduce ----
  if (wv == 1){
    float acc = 0.0f;
    if (ln == 0){
      const float dx = ini[0] - a1x;   // a1 differs only in x; a0 diff = 0
      const float dy = ini[1] - a2x;   // a2 differs in x,y (z = 0)
      const float dz = ini[2] - a2y;
      acc = dx*dx + dy*dy + dz*dz;
    }
    #pragma unroll
    for (int k = 0; k < CHUNK; ++k){
      if (j0 + k < NSTEP){
        const int o = ln*49 + 3*k;
        const float dx = pos[o]   - tl[k][0];
        const float dy = pos[o+1] - tl[k][1];
        const float dz = pos[o+2] - tl[k][2];
        acc = fmaf(dx, dx, acc);
        acc = fmaf(dy, dy, acc);
        acc = fmaf(dz, dz, acc);
      }
    }
    #pragma unroll
    for (int off = 32; off > 0; off >>= 1) acc += __shfl_down(acc, off);
    if (ln == 0) atomicAdd(out, acc * INVMEAN);
  }
}

extern "C" void kernel_launch(void* const* d_in, const int* in_sizes, int n_in,
                              void* d_out, int out_size, void* d_ws, size_t ws_size,
                              hipStream_t stream) {
  const float* pred = (const float*)d_in[0];
  const float* targ = (const float*)d_in[1];
  float* out = (float*)d_out;

  hipMemsetAsync(d_out, 0, sizeof(float), stream);
  rmsd_kernel<<<NROW, 128, 0, stream>>>(pred, targ, out);
}

// Round 9
// 126.701 us; speedup vs baseline: 1.2425x; 1.0367x over previous
//
#include <hip/hip_runtime.h>

// rmsdLoss via associative affine scan — one wave per chain, CHUNK=16.
// LDS holds step vectors P_j = l*what_j packed per k-slab:
//   [k][0..65]   : Px  (fp32)   lane ln at [ln]
//   [k][66..131] : (Py,Pz) packed bf16x2 (one dword)
// -> 16.9 KB for both chains (9 blocks/CU), 2 LDS reads/step 264 B apart
//    (ds_read2-able), stride-1 conflict-free.
// Step algebra (verified R8): q = rsqrt(P.P), what = q*P = (hx,hy,hz),
//   ist = rsqrt(hy^2+hz^2)  [cancellation-free st],
//   u = M*P; t += u; c0' = q*u; c1' = ist*(hx*c0' - c0); c2' = ist*(hy*c2 - hz*c1).
// Frame orthonormality is preserved w.r.t. the STORED (packed) P, so bf16
// packing of (Py,Pz) only perturbs the effective chi/theta by ~0.3% (well-
// conditioned); Px (clamp-sensitive) stays fp32.
// Block = 128 thr = 2 waves: wv0 = pred (clipped), wv1 = targ; lane ln owns
// steps [16ln,16ln+16). 6-level shuffle scan -> exclusive prefix E; fold
// (F0,a2) -> G; positions p_k = G.t + G.M*tl[k] (snapshot, no replay).
// Pred positions cross via pitch-49 pos buffer aliasing the dead P arena
// (barrier-protected).

#define LROW  4087
#define NSTEP 1021
#define NROW  2048
#define CHUNK 16
#define SLAB  132                // 66 Px + 66 PyPz per k
#define EPSF  1e-6f
#define INVMEAN (1.0f / (2048.0f * 1024.0f * 3.0f))

__device__ __forceinline__ float frcp(float x){ return __builtin_amdgcn_rcpf(x); }
__device__ __forceinline__ float frsq(float x){ return __builtin_amdgcn_rsqf(x); }

__device__ __forceinline__ unsigned pk_bf16(float y, float z){
  unsigned by = __float_as_uint(y);
  by = (by + 0x7FFFu + ((by >> 16) & 1u)) >> 16;          // rne -> low half
  unsigned bz = __float_as_uint(z);
  bz = (bz + 0x7FFFu + ((bz >> 16) & 1u)) & 0xFFFF0000u;  // rne -> high half
  return bz | by;
}

struct Xf { float f[12]; };  // COLUMN-major: f[0..2]=c0, f[3..5]=c1, f[6..8]=c2, f[9..11]=t

__device__ __forceinline__ Xf xident(){
  Xf X;
  X.f[0]=1.f; X.f[1]=0.f; X.f[2]=0.f;
  X.f[3]=0.f; X.f[4]=1.f; X.f[5]=0.f;
  X.f[6]=0.f; X.f[7]=0.f; X.f[8]=1.f;
  X.f[9]=0.f; X.f[10]=0.f; X.f[11]=0.f;
  return X;
}

// A applied first, then B: C.M = A.M*B.M (columns), C.t = A.t + A.M*B.t
__device__ __forceinline__ Xf xcombine(const Xf& A, const Xf& B){
  Xf C;
  #pragma unroll
  for (int c3 = 0; c3 < 12; c3 += 3){
    const float bx = B.f[c3], by = B.f[c3+1], bz = B.f[c3+2];
    C.f[c3]   = A.f[0]*bx + A.f[3]*by + A.f[6]*bz;
    C.f[c3+1] = A.f[1]*bx + A.f[4]*by + A.f[7]*bz;
    C.f[c3+2] = A.f[2]*bx + A.f[5]*by + A.f[8]*bz;
  }
  C.f[9] += A.f[9]; C.f[10] += A.f[10]; C.f[11] += A.f[11];
  return C;
}

__device__ __forceinline__ void xstepP(Xf& X, float Px, float Py, float Pz){
  const float l2 = Px*Px + Py*Py + Pz*Pz;
  const float q  = frsq(l2);
  const float hx = q*Px, hy = q*Py, hz = q*Pz;
  const float ist = frsq(fmaxf(hy*hy + hz*hz, 1e-12f));   // 1/st, cancellation-free
  const float ux = X.f[0]*Px + X.f[3]*Py + X.f[6]*Pz;
  const float uy = X.f[1]*Px + X.f[4]*Py + X.f[7]*Pz;
  const float uz = X.f[2]*Px + X.f[5]*Py + X.f[8]*Pz;
  X.f[9] += ux; X.f[10] += uy; X.f[11] += uz;
  const float n0x = q*ux, n0y = q*uy, n0z = q*uz;
  const float n1x = ist*(hx*n0x - X.f[0]);
  const float n1y = ist*(hx*n0y - X.f[1]);
  const float n1z = ist*(hx*n0z - X.f[2]);
  const float n2x = ist*(hy*X.f[6] - hz*X.f[3]);
  const float n2y = ist*(hy*X.f[7] - hz*X.f[4]);
  const float n2z = ist*(hy*X.f[8] - hz*X.f[5]);
  X.f[0]=n0x; X.f[1]=n0y; X.f[2]=n0z;
  X.f[3]=n1x; X.f[4]=n1y; X.f[5]=n1z;
  X.f[6]=n2x; X.f[7]=n2y; X.f[8]=n2z;
}

__device__ __forceinline__ void xinitP(Xf& X, float Px, float Py, float Pz){
  const float l2 = Px*Px + Py*Py + Pz*Pz;
  const float q  = frsq(l2);
  const float hx = q*Px, hy = q*Py, hz = q*Pz;
  const float s2 = fmaxf(hy*hy + hz*hz, 1e-12f);
  const float ist = frsq(s2);
  const float st  = s2 * ist;
  X.f[0]=hx;        X.f[1]=hy;          X.f[2]=hz;
  X.f[3]=-st;       X.f[4]=hx*hy*ist;   X.f[5]=hx*hz*ist;
  X.f[6]=0.f;       X.f[7]=-hz*ist;     X.f[8]=hy*ist;
  X.f[9]=Px;        X.f[10]=Py;         X.f[11]=Pz;
}

__global__ void __launch_bounds__(128, 4)
rmsd_kernel(const float* __restrict__ pred, const float* __restrict__ targ,
            float* __restrict__ out){
  __shared__ float Parena[2][CHUNK][SLAB];   // 16.9 KB
  __shared__ float ini[3];                   // pred a1x, a2x, a2y

  const int row = blockIdx.x;
  const int tid = threadIdx.x;
  const int ln  = tid & 63;
  const int wv  = tid >> 6;      // 0 = pred, 1 = targ
  const int j0  = ln * CHUNK;

  const float* __restrict__ vp = pred + (size_t)row * LROW;
  const float* __restrict__ vt = targ + (size_t)row * LROW;

  // early broadcast loads for the fold (own chain)
  const float* vw = wv ? vt : vp;
  const float lw = wv ? 1e30f : 1.0f;
  const float rb0 = fminf(fmaxf(vw[3064], -lw), lw);
  const float rd0 = fminf(fmaxf(vw[2042], -lw), lw);
  const float rb1w= fminf(fmaxf(vw[3065], -lw), lw);

  // ---- staging: compute P_j, store Px fp32 + (Py,Pz) bf16x2 ----
  for (int u = tid; u < 2048; u += 128){
    const int c = u >> 10;
    const int j = u & 1023;
    if (j < NSTEP){
      const float* v = c ? vt : vp;
      const float cl = c ? 1e30f : 1.0f;     // reference clips pred only
      const float s0  = fminf(fmaxf(v[2*j],    -cl), cl);
      const float s1  = fminf(fmaxf(v[2*j+1],  -cl), cl);
      const float rd  = fminf(fmaxf(v[2043+j], -cl), cl);
      const float rb1 = fminf(fmaxf(v[3065+j], -cl), cl);
      const float rb2 = fminf(fmaxf(v[3066+j], -cl), cl);
      const float d  = fmaf(rd,  1.75f, 3.25f);
      const float b1 = fmaf(rb1, 1.05f, 1.95f);
      const float b2 = fmaf(rb2, 1.05f, 1.95f);
      float ct = (b1*b1 + b2*b2 - d*d) * frcp(2.0f*b1*b2);
      ct = fminf(fmaxf(ct, -1.0f + EPSF), 1.0f - EPSF);
      const float st = sqrtf(fmaxf(1.0f - ct*ct, 0.0f));
      const float r2 = s0*s0 + s1*s1;
      const bool ok = r2 > 1e-36f;
      const float ir = ok ? frcp(sqrtf(r2)) : 0.0f;
      const float scv = s0 * ir;
      const float ccv = ok ? s1 * ir : 1.0f;
      float* slab = &Parena[c][j & 15][j >> 4];
      slab[0] = -b2 * ct;
      ((unsigned*)slab)[66] = pk_bf16(b2 * st * ccv, b2 * st * scv);
    }
  }
  __syncthreads();

  // ---- phase 1: per-lane chunk compose, snapshot local-prefix translations ----
  Xf X;
  float tl[CHUNK][3];
  {
    const float* base = &Parena[wv][0][ln];
    const float Px = base[0];
    const unsigned pz = ((const unsigned*)base)[66];
    xinitP(X, Px, __uint_as_float(pz << 16), __uint_as_float(pz & 0xFFFF0000u));
  }
  tl[0][0]=X.f[9]; tl[0][1]=X.f[10]; tl[0][2]=X.f[11];
  #pragma unroll
  for (int k = 1; k < CHUNK; ++k){
    if (j0 + k < NSTEP){
      const float* base = &Parena[wv][k][ln];
      const float Px = base[0];
      const unsigned pz = ((const unsigned*)base)[66];
      xstepP(X, Px, __uint_as_float(pz << 16), __uint_as_float(pz & 0xFFFF0000u));
    }
    tl[k][0]=X.f[9]; tl[k][1]=X.f[10]; tl[k][2]=X.f[11];
  }

  // ---- in-wave inclusive scan (Hillis-Steele, non-commutative) ----
  #pragma unroll
  for (int off = 1; off < 64; off <<= 1){
    Xf o;
    #pragma unroll
    for (int i = 0; i < 12; ++i) o.f[i] = __shfl_up(X.f[i], off);
    if (ln >= off) X = xcombine(o, X);
  }
  Xf E;
  #pragma unroll
  for (int i = 0; i < 12; ++i) E.f[i] = __shfl_up(X.f[i], 1);
  if (ln == 0) E = xident();

  // ---- fold (F0, a2): G = F0*E.M ; G.t = a2 + F0*E.t ----
  const float bl0 = fmaf(rb0,  1.05f, 1.95f);
  const float d0  = fmaf(rd0,  1.75f, 3.25f);
  const float b1f = fmaf(rb1w, 1.05f, 1.95f);
  float ct0 = (bl0*bl0 + b1f*b1f - d0*d0) * frcp(2.0f*bl0*b1f);
  ct0 = fminf(fmaxf(ct0, -1.0f + EPSF), 1.0f - EPSF);
  const float st0 = sqrtf(fmaxf(1.0f - ct0*ct0, 0.0f));
  const float a1x = bl0;
  const float a2x = bl0 - b1f*ct0;
  const float a2y = b1f*st0;

  Xf G;   // F0 rows: (-ct0,-st0,0),(st0,-ct0,0),(0,0,1) applied to each column + t
  #pragma unroll
  for (int c3 = 0; c3 < 12; c3 += 3){
    const float ex = E.f[c3], ey = E.f[c3+1], ez = E.f[c3+2];
    G.f[c3]   = -ct0*ex - st0*ey;
    G.f[c3+1] =  st0*ex - ct0*ey;
    G.f[c3+2] =  ez;
  }
  G.f[9] += a2x; G.f[10] += a2y;

  // ---- positions p_k = G.t + G.M * tl[k]  (in place) ----
  #pragma unroll
  for (int k = 0; k < CHUNK; ++k){
    const float tx = tl[k][0], ty = tl[k][1], tz = tl[k][2];
    tl[k][0] = G.f[9]  + G.f[0]*tx + G.f[3]*ty + G.f[6]*tz;
    tl[k][1] = G.f[10] + G.f[1]*tx + G.f[4]*ty + G.f[7]*tz;
    tl[k][2] = G.f[11] + G.f[2]*tx + G.f[5]*ty + G.f[8]*tz;
  }

  __syncthreads();   // P arena dead for BOTH waves -> safe to reuse as pos

  // ---- pred publishes positions into the dead P arena ----
  float* pos = &Parena[0][0][0];   // pitch 49: max 63*49+45+2 = 3134 < 4224
  if (wv == 0){
    #pragma unroll
    for (int k = 0; k < CHUNK; ++k){
      if (j0 + k < NSTEP){
        const int o = ln*49 + 3*k;
        pos[o] = tl[k][0]; pos[o+1] = tl[k][1]; pos[o+2] = tl[k][2];
      }
    }
    if (ln == 0){ ini[0] = a1x; ini[1] = a2x; ini[2] = a2y; }
  }
  __syncthreads();

  // ---- targ wave: diff + reduce ----
  if (wv == 1){
    float acc = 0.0f;
    if (ln == 0){
      const float dx = ini[0] - a1x;   // a1 differs only in x; a0 diff = 0
      const float dy = ini[1] - a2x;   // a2 differs in x,y (z = 0)
      const float dz = ini[2] - a2y;
      acc = dx*dx + dy*dy + dz*dz;
    }
    #pragma unroll
    for (int k = 0; k < CHUNK; ++k){
      if (j0 + k < NSTEP){
        const int o = ln*49 + 3*k;
        const float dx = pos[o]   - tl[k][0];
        const float dy = pos[o+1] - tl[k][1];
        const float dz = pos[o+2] - tl[k][2];
        acc = fmaf(dx, dx, acc);
        acc = fmaf(dy, dy, acc);
        acc = fmaf(dz, dz, acc);
      }
    }
    #pragma unroll
    for (int off = 32; off > 0; off >>= 1) acc += __shfl_down(acc, off);
    if (ln == 0) atomicAdd(out, acc * INVMEAN);
  }
}

extern "C" void kernel_launch(void* const* d_in, const int* in_sizes, int n_in,
                              void* d_out, int out_size, void* d_ws, size_t ws_size,
                              hipStream_t stream) {
  const float* pred = (const float*)d_in[0];
  const float* targ = (const float*)d_in[1];
  float* out = (float*)d_out;

  hipMemsetAsync(d_out, 0, sizeof(float), stream);
  rmsd_kernel<<<NROW, 128, 0, stream>>>(pred, targ, out);
}

// Round 10
// 122.858 us; speedup vs baseline: 1.2813x; 1.0313x over previous
//
#include <hip/hip_runtime.h>

// rmsdLoss via associative affine scan — one wave per chain, CHUNK=16.
// R10 = R9 + explicit load batching (the R9 profile showed 820 GB/s /10% peak:
// staging loads were latency-serialized at VGPR=64). Staging now preloads all
// 80 input dwords per thread into registers (independent, coalesced), then
// computes P; phase 1 preloads all 32 LDS dwords before the dependent chain.
//
// LDS: P_j = l*what_j packed per k-slab: [k][0..65] Px fp32 (lane ln at [ln]),
// [k][66..131] (Py,Pz) bf16x2. 16.9 KB both chains. Step algebra (verified
// R8/R9): q=rsqrt(P.P), h=q*P, ist=rsqrt(hy^2+hz^2) [cancellation-free st];
// u=M*P; t+=u; c0'=q*u; c1'=ist*(hx*c0'-c0); c2'=ist*(hy*c2-hz*c1).
// Block = 128 thr = 2 waves: wv0 = pred (clipped), wv1 = targ; lane ln owns
// steps [16ln,16ln+16). 6-level shuffle scan -> exclusive prefix E; fold
// (F0,a2) -> G; positions p_k = G.t + G.M*tl[k] (snapshot, no replay).
// Pred positions cross via pitch-49 pos buffer aliasing the dead P arena.

#define LROW  4087
#define NSTEP 1021
#define NROW  2048
#define CHUNK 16
#define SLAB  132                // 66 Px + 66 PyPz per k
#define EPSF  1e-6f
#define INVMEAN (1.0f / (2048.0f * 1024.0f * 3.0f))

__device__ __forceinline__ float frcp(float x){ return __builtin_amdgcn_rcpf(x); }
__device__ __forceinline__ float frsq(float x){ return __builtin_amdgcn_rsqf(x); }

__device__ __forceinline__ unsigned pk_bf16(float y, float z){
  unsigned by = __float_as_uint(y);
  by = (by + 0x7FFFu + ((by >> 16) & 1u)) >> 16;          // rne -> low half
  unsigned bz = __float_as_uint(z);
  bz = (bz + 0x7FFFu + ((bz >> 16) & 1u)) & 0xFFFF0000u;  // rne -> high half
  return bz | by;
}

struct Xf { float f[12]; };  // COLUMN-major: f[0..2]=c0, f[3..5]=c1, f[6..8]=c2, f[9..11]=t

__device__ __forceinline__ Xf xident(){
  Xf X;
  X.f[0]=1.f; X.f[1]=0.f; X.f[2]=0.f;
  X.f[3]=0.f; X.f[4]=1.f; X.f[5]=0.f;
  X.f[6]=0.f; X.f[7]=0.f; X.f[8]=1.f;
  X.f[9]=0.f; X.f[10]=0.f; X.f[11]=0.f;
  return X;
}

// A applied first, then B: C.M = A.M*B.M (columns), C.t = A.t + A.M*B.t
__device__ __forceinline__ Xf xcombine(const Xf& A, const Xf& B){
  Xf C;
  #pragma unroll
  for (int c3 = 0; c3 < 12; c3 += 3){
    const float bx = B.f[c3], by = B.f[c3+1], bz = B.f[c3+2];
    C.f[c3]   = A.f[0]*bx + A.f[3]*by + A.f[6]*bz;
    C.f[c3+1] = A.f[1]*bx + A.f[4]*by + A.f[7]*bz;
    C.f[c3+2] = A.f[2]*bx + A.f[5]*by + A.f[8]*bz;
  }
  C.f[9] += A.f[9]; C.f[10] += A.f[10]; C.f[11] += A.f[11];
  return C;
}

__device__ __forceinline__ void xstepP(Xf& X, float Px, float Py, float Pz){
  const float l2 = Px*Px + Py*Py + Pz*Pz;
  const float q  = frsq(l2);
  const float hx = q*Px, hy = q*Py, hz = q*Pz;
  const float ist = frsq(fmaxf(hy*hy + hz*hz, 1e-12f));   // 1/st, cancellation-free
  const float ux = X.f[0]*Px + X.f[3]*Py + X.f[6]*Pz;
  const float uy = X.f[1]*Px + X.f[4]*Py + X.f[7]*Pz;
  const float uz = X.f[2]*Px + X.f[5]*Py + X.f[8]*Pz;
  X.f[9] += ux; X.f[10] += uy; X.f[11] += uz;
  const float n0x = q*ux, n0y = q*uy, n0z = q*uz;
  const float n1x = ist*(hx*n0x - X.f[0]);
  const float n1y = ist*(hx*n0y - X.f[1]);
  const float n1z = ist*(hx*n0z - X.f[2]);
  const float n2x = ist*(hy*X.f[6] - hz*X.f[3]);
  const float n2y = ist*(hy*X.f[7] - hz*X.f[4]);
  const float n2z = ist*(hy*X.f[8] - hz*X.f[5]);
  X.f[0]=n0x; X.f[1]=n0y; X.f[2]=n0z;
  X.f[3]=n1x; X.f[4]=n1y; X.f[5]=n1z;
  X.f[6]=n2x; X.f[7]=n2y; X.f[8]=n2z;
}

__device__ __forceinline__ void xinitP(Xf& X, float Px, float Py, float Pz){
  const float l2 = Px*Px + Py*Py + Pz*Pz;
  const float q  = frsq(l2);
  const float hx = q*Px, hy = q*Py, hz = q*Pz;
  const float s2 = fmaxf(hy*hy + hz*hz, 1e-12f);
  const float ist = frsq(s2);
  const float st  = s2 * ist;
  X.f[0]=hx;        X.f[1]=hy;          X.f[2]=hz;
  X.f[3]=-st;       X.f[4]=hx*hy*ist;   X.f[5]=hx*hz*ist;
  X.f[6]=0.f;       X.f[7]=-hz*ist;     X.f[8]=hy*ist;
  X.f[9]=Px;        X.f[10]=Py;         X.f[11]=Pz;
}

__global__ void __launch_bounds__(128, 4)
rmsd_kernel(const float* __restrict__ pred, const float* __restrict__ targ,
            float* __restrict__ out){
  __shared__ float Parena[2][CHUNK][SLAB];   // 16.9 KB
  __shared__ float ini[3];                   // pred a1x, a2x, a2y

  const int row = blockIdx.x;
  const int tid = threadIdx.x;
  const int ln  = tid & 63;
  const int wv  = tid >> 6;      // 0 = pred, 1 = targ
  const int j0  = ln * CHUNK;

  const float* __restrict__ vp = pred + (size_t)row * LROW;
  const float* __restrict__ vt = targ + (size_t)row * LROW;

  // early broadcast loads for the fold (own chain)
  const float* vw = wv ? vt : vp;
  const float lw = wv ? 1e30f : 1.0f;
  const float rb0 = fminf(fmaxf(vw[3064], -lw), lw);
  const float rd0 = fminf(fmaxf(vw[2042], -lw), lw);
  const float rb1w= fminf(fmaxf(vw[3065], -lw), lw);

  // ---- staging phase A: batch-load ALL raw inputs (80 independent dwords) ----
  // i in [0,8): pred steps j = tid + 128*i ; i in [8,16): targ, same j.
  float s0a[16], s1a[16], rda[16], r1a[16], r2a[16];
  #pragma unroll
  for (int i = 0; i < 16; ++i){
    const int j = tid + ((i & 7) << 7);          // 0..1023
    const float* v = (i < 8) ? vp : vt;
    int i1 = 3065 + j; if (i1 > 4086) i1 = 4086; // j>1020 lanes: clamp (unused)
    int i2 = 3066 + j; if (i2 > 4086) i2 = 4086;
    s0a[i] = v[2*j];
    s1a[i] = v[2*j+1];
    rda[i] = v[2043+j];
    r1a[i] = v[i1];
    r2a[i] = v[i2];
  }

  // ---- staging phase B: compute P_j, store Px fp32 + (Py,Pz) bf16x2 ----
  #pragma unroll
  for (int i = 0; i < 16; ++i){
    const int j = tid + ((i & 7) << 7);
    if (j < NSTEP){
      const int c = i >> 3;
      const float cl = c ? 1e30f : 1.0f;     // reference clips pred only
      const float s0  = fminf(fmaxf(s0a[i], -cl), cl);
      const float s1  = fminf(fmaxf(s1a[i], -cl), cl);
      const float rd  = fminf(fmaxf(rda[i], -cl), cl);
      const float rb1 = fminf(fmaxf(r1a[i], -cl), cl);
      const float rb2 = fminf(fmaxf(r2a[i], -cl), cl);
      const float d  = fmaf(rd,  1.75f, 3.25f);
      const float b1 = fmaf(rb1, 1.05f, 1.95f);
      const float b2 = fmaf(rb2, 1.05f, 1.95f);
      float ct = (b1*b1 + b2*b2 - d*d) * frcp(2.0f*b1*b2);
      ct = fminf(fmaxf(ct, -1.0f + EPSF), 1.0f - EPSF);
      const float st = sqrtf(fmaxf(1.0f - ct*ct, 0.0f));
      const float r2 = s0*s0 + s1*s1;
      const bool ok = r2 > 1e-36f;
      const float ir = ok ? frcp(sqrtf(r2)) : 0.0f;
      const float scv = s0 * ir;
      const float ccv = ok ? s1 * ir : 1.0f;
      float* slab = &Parena[c][j & 15][j >> 4];
      slab[0] = -b2 * ct;
      ((unsigned*)slab)[66] = pk_bf16(b2 * st * ccv, b2 * st * scv);
    }
  }
  __syncthreads();

  // ---- phase 1 preload: all 16 steps' (Px, PyPz) from LDS up front ----
  float    Pxa[CHUNK];
  unsigned Pza[CHUNK];
  #pragma unroll
  for (int k = 0; k < CHUNK; ++k){
    const float* base = &Parena[wv][k][ln];
    Pxa[k] = base[0];
    Pza[k] = ((const unsigned*)base)[66];
  }

  // ---- phase 1: per-lane chunk compose, snapshot local-prefix translations ----
  Xf X;
  float tl[CHUNK][3];
  xinitP(X, Pxa[0], __uint_as_float(Pza[0] << 16), __uint_as_float(Pza[0] & 0xFFFF0000u));
  tl[0][0]=X.f[9]; tl[0][1]=X.f[10]; tl[0][2]=X.f[11];
  #pragma unroll
  for (int k = 1; k < CHUNK; ++k){
    if (j0 + k < NSTEP)
      xstepP(X, Pxa[k], __uint_as_float(Pza[k] << 16), __uint_as_float(Pza[k] & 0xFFFF0000u));
    tl[k][0]=X.f[9]; tl[k][1]=X.f[10]; tl[k][2]=X.f[11];
  }

  // ---- in-wave inclusive scan (Hillis-Steele, non-commutative) ----
  #pragma unroll
  for (int off = 1; off < 64; off <<= 1){
    Xf o;
    #pragma unroll
    for (int i = 0; i < 12; ++i) o.f[i] = __shfl_up(X.f[i], off);
    if (ln >= off) X = xcombine(o, X);
  }
  Xf E;
  #pragma unroll
  for (int i = 0; i < 12; ++i) E.f[i] = __shfl_up(X.f[i], 1);
  if (ln == 0) E = xident();

  // ---- fold (F0, a2): G = F0*E.M ; G.t = a2 + F0*E.t ----
  const float bl0 = fmaf(rb0,  1.05f, 1.95f);
  const float d0  = fmaf(rd0,  1.75f, 3.25f);
  const float b1f = fmaf(rb1w, 1.05f, 1.95f);
  float ct0 = (bl0*bl0 + b1f*b1f - d0*d0) * frcp(2.0f*bl0*b1f);
  ct0 = fminf(fmaxf(ct0, -1.0f + EPSF), 1.0f - EPSF);
  const float st0 = sqrtf(fmaxf(1.0f - ct0*ct0, 0.0f));
  const float a1x = bl0;
  const float a2x = bl0 - b1f*ct0;
  const float a2y = b1f*st0;

  Xf G;   // F0 rows: (-ct0,-st0,0),(st0,-ct0,0),(0,0,1) applied to each column + t
  #pragma unroll
  for (int c3 = 0; c3 < 12; c3 += 3){
    const float ex = E.f[c3], ey = E.f[c3+1], ez = E.f[c3+2];
    G.f[c3]   = -ct0*ex - st0*ey;
    G.f[c3+1] =  st0*ex - ct0*ey;
    G.f[c3+2] =  ez;
  }
  G.f[9] += a2x; G.f[10] += a2y;

  // ---- positions p_k = G.t + G.M * tl[k]  (in place) ----
  #pragma unroll
  for (int k = 0; k < CHUNK; ++k){
    const float tx = tl[k][0], ty = tl[k][1], tz = tl[k][2];
    tl[k][0] = G.f[9]  + G.f[0]*tx + G.f[3]*ty + G.f[6]*tz;
    tl[k][1] = G.f[10] + G.f[1]*tx + G.f[4]*ty + G.f[7]*tz;
    tl[k][2] = G.f[11] + G.f[2]*tx + G.f[5]*ty + G.f[8]*tz;
  }

  __syncthreads();   // P arena dead for BOTH waves -> safe to reuse as pos

  // ---- pred publishes positions into the dead P arena ----
  float* pos = &Parena[0][0][0];   // pitch 49: max 63*49+45+2 = 3134 < 4224
  if (wv == 0){
    #pragma unroll
    for (int k = 0; k < CHUNK; ++k){
      if (j0 + k < NSTEP){
        const int o = ln*49 + 3*k;
        pos[o] = tl[k][0]; pos[o+1] = tl[k][1]; pos[o+2] = tl[k][2];
      }
    }
    if (ln == 0){ ini[0] = a1x; ini[1] = a2x; ini[2] = a2y; }
  }
  __syncthreads();

  // ---- targ wave: diff + reduce ----
  if (wv == 1){
    float acc = 0.0f;
    if (ln == 0){
      const float dx = ini[0] - a1x;   // a1 differs only in x; a0 diff = 0
      const float dy = ini[1] - a2x;   // a2 differs in x,y (z = 0)
      const float dz = ini[2] - a2y;
      acc = dx*dx + dy*dy + dz*dz;
    }
    #pragma unroll
    for (int k = 0; k < CHUNK; ++k){
      if (j0 + k < NSTEP){
        const int o = ln*49 + 3*k;
        const float dx = pos[o]   - tl[k][0];
        const float dy = pos[o+1] - tl[k][1];
        const float dz = pos[o+2] - tl[k][2];
        acc = fmaf(dx, dx, acc);
        acc = fmaf(dy, dy, acc);
        acc = fmaf(dz, dz, acc);
      }
    }
    #pragma unroll
    for (int off = 32; off > 0; off >>= 1) acc += __shfl_down(acc, off);
    if (ln == 0) atomicAdd(out, acc * INVMEAN);
  }
}

extern "C" void kernel_launch(void* const* d_in, const int* in_sizes, int n_in,
                              void* d_out, int out_size, void* d_ws, size_t ws_size,
                              hipStream_t stream) {
  const float* pred = (const float*)d_in[0];
  const float* targ = (const float*)d_in[1];
  float* out = (float*)d_out;

  hipMemsetAsync(d_out, 0, sizeof(float), stream);
  rmsd_kernel<<<NROW, 128, 0, stream>>>(pred, targ, out);
}